// Round 8
// baseline (438.630 us; speedup 1.0000x reference)
//
#include <hip/hip_runtime.h>
#include <math.h>

#define NN 50000
#define NE 800000
#define IC 256
#define EPS 1e-5f

typedef __attribute__((ext_vector_type(8))) short short8;   // 8 bf16 (4 VGPRs)
typedef __attribute__((ext_vector_type(4))) float f32x4;    // MFMA acc

// ---------------- ws layout (float offsets) ----------------
enum : int {
  OFF_S1     = 0,                        // [256] zeroed
  OFF_S2     = 256,                      // [256] zeroed
  OFF_COUNTS = 512,                      // int[NN] zeroed
  ZERO_END   = OFF_COUNTS + 50000,       // 50512
  OFF_CURSOR = ZERO_END,                 // int[NN]
  OFF_START  = OFF_CURSOR + 50000,       // int[NN+1] pad 50004
  OFF_BSUM   = OFF_START + 50004,        // int[64] (unused, keep layout)
  OFF_BOFF   = OFF_BSUM + 64,            // int[64] (unused, keep layout)
  OFF_ALS    = OFF_BOFF + 64,            // [NN*4] (16B aligned)
  OFF_ALD    = OFF_ALS + 200000,
  OFF_SRCS   = OFF_ALD + 200000,         // int[NE]
  OFF_Y32    = OFF_SRCS + 800000,        // float2[NN]
  OFF_ND4    = OFF_Y32 + 100000,         // float4[NN] = (al3s, h3x, h3y, al3d)
  OFF_BFH    = OFF_ND4 + 200000,         // ushort[131072]
  OFF_BFL    = OFF_BFH + 65536,
  OFF_HBF    = OFF_BFL + 65536,          // ushort[NN*256]
  OFF_YLBF   = OFF_HBF + 6400000,        // ushort[NN*256]; becomes x1 in place
  WS_FLOATS  = OFF_YLBF + 6400000        // ~58 MB
};

__device__ __forceinline__ float lrelu(float s) { return s > 0.f ? s : 0.2f * s; }
__device__ __forceinline__ float b2f(unsigned short u) {
  return __uint_as_float(((unsigned)u) << 16);
}
__device__ __forceinline__ unsigned short f2bf(float f) {  // RNE
  unsigned u = __float_as_uint(f);
  return (unsigned short)((u + 0x7fffu + ((u >> 16) & 1u)) >> 16);
}

// ---------------- fused prologue: BN1 stats | edge histogram | weight prep -------
// blocks [0,1024): column sums of x; [1024,4149): dst histogram; [4149,4661): prepB
__global__ __launch_bounds__(256) void k_prep(const float* __restrict__ x,
                                              float* __restrict__ S1,
                                              float* __restrict__ S2,
                                              const int* __restrict__ dst,
                                              int* __restrict__ counts,
                                              const float* __restrict__ Wlin,
                                              const float* __restrict__ Wcon,
                                              unsigned short* __restrict__ Bfh,
                                              unsigned short* __restrict__ Bfl) {
  int b = blockIdx.x;
  if (b < 1024) {
    int c = threadIdx.x;
    float s1 = 0.f, s2 = 0.f;
    for (int r = b; r < NN; r += 1024) {
      float v = x[r * IC + c];
      s1 += v;
      s2 = fmaf(v, v, s2);
    }
    atomicAdd(&S1[c], s1);
    atomicAdd(&S2[c], s2);
  } else if (b < 4149) {
    int e = (b - 1024) * 256 + threadIdx.x;  // exactly NE
    atomicAdd(&counts[dst[e]], 1);
  } else {
    int id = (b - 4149) * 256 + threadIdx.x;  // < 131072
    int j = id & 7, lane = (id >> 3) & 63, nt = (id >> 9) & 31, ks = id >> 14;
    int k = ks * 32 + ((lane >> 4) << 3) + j;
    int n = nt * 16 + (lane & 15);
    float v = (n < 256) ? Wlin[k * 256 + n] : Wcon[k * 256 + (n - 256)];
    unsigned short h = f2bf(v);
    Bfh[id] = h;
    Bfl[id] = f2bf(v - b2f(h));
  }
}

// ---------------- BN stats (layer 2, bf16 input) ----------------
__global__ __launch_bounds__(256) void k_bnstats2(const unsigned short* __restrict__ x1,
                                                  float* __restrict__ S1,
                                                  float* __restrict__ S2) {
  int c = threadIdx.x;
  float s1 = 0.f, s2 = 0.f;
  for (int r = blockIdx.x; r < NN; r += gridDim.x) {
    float v = b2f(x1[r * IC + c]);
    s1 += v;
    s2 = fmaf(v, v, s2);
  }
  atomicAdd(&S1[c], s1);
  atomicAdd(&S2[c], s2);
}

// ---------------- MFMA dual GEMM, fused BN-finalize + alpha ----------
// grid (2, 782): block = 64 rows x 256 cols. bn=0 -> ylbf, bn=1 -> hbf + logits.
__global__ __launch_bounds__(256, 4) void k_gemm(const float* __restrict__ x,
                                                 const float* __restrict__ S1,
                                                 const float* __restrict__ S2,
                                                 const float* __restrict__ bng,
                                                 const float* __restrict__ bnb,
                                                 const unsigned short* __restrict__ Bfh,
                                                 const unsigned short* __restrict__ Bfl,
                                                 unsigned short* __restrict__ ylbf,
                                                 unsigned short* __restrict__ hbf,
                                                 const float* __restrict__ asrc,
                                                 const float* __restrict__ adst,
                                                 float* __restrict__ als,
                                                 float* __restrict__ ald) {
  __shared__ unsigned short Ah[2048], Al[2048];
  __shared__ float sc[256], sh[256];
  const int tid = threadIdx.x;
  const int bn = blockIdx.x;
  const int row0 = blockIdx.y * 64;
  const int wave = tid >> 6, lane = tid & 63;
  {
    float mu = S1[tid] * (1.f / NN);
    float var = S2[tid] * (1.f / NN) - mu * mu;
    float ss = bng[tid] / sqrtf(var + EPS);
    sc[tid] = ss;
    sh[tid] = bnb[tid] - mu * ss;
  }
  const float4* x4 = (const float4*)x;
  const short8* Bh8 = (const short8*)Bfh;
  const short8* Bl8 = (const short8*)Bfl;
  f32x4 acc[4][4];
#pragma unroll
  for (int i = 0; i < 4; ++i)
#pragma unroll
    for (int j = 0; j < 4; ++j) acc[i][j] = (f32x4){0.f, 0.f, 0.f, 0.f};

  const int m = tid >> 2, kg = tid & 3;
  const int r = row0 + m;
  const int aaddr = (((m >> 4) * 64) + ((m & 15) | (kg << 4))) * 8;
  __syncthreads();

  for (int ks = 0; ks < 8; ++ks) {
    const int c0 = ks * 32 + kg * 8;
    float v[8];
    if (r < NN) {
      int base = (r * IC + c0) >> 2;
      float4 fa = x4[base], fb = x4[base + 1];
      v[0] = fa.x; v[1] = fa.y; v[2] = fa.z; v[3] = fa.w;
      v[4] = fb.x; v[5] = fb.y; v[6] = fb.z; v[7] = fb.w;
#pragma unroll
      for (int j = 0; j < 8; ++j) v[j] = fmaf(v[j], sc[c0 + j], sh[c0 + j]);
    } else {
#pragma unroll
      for (int j = 0; j < 8; ++j) v[j] = 0.f;
    }
    unsigned ph[4], pl[4];
#pragma unroll
    for (int j = 0; j < 4; ++j) {
      unsigned short h0 = f2bf(v[2 * j]), h1 = f2bf(v[2 * j + 1]);
      unsigned short l0 = f2bf(v[2 * j] - b2f(h0));
      unsigned short l1 = f2bf(v[2 * j + 1] - b2f(h1));
      ph[j] = (unsigned)h0 | ((unsigned)h1 << 16);
      pl[j] = (unsigned)l0 | ((unsigned)l1 << 16);
    }
    *(uint4*)&Ah[aaddr] = make_uint4(ph[0], ph[1], ph[2], ph[3]);
    *(uint4*)&Al[aaddr] = make_uint4(pl[0], pl[1], pl[2], pl[3]);
    __syncthreads();

    short8 ah[4], alo[4];
#pragma unroll
    for (int mt = 0; mt < 4; ++mt) {
      ah[mt] = *(const short8*)&Ah[(mt * 64 + lane) * 8];
      alo[mt] = *(const short8*)&Al[(mt * 64 + lane) * 8];
    }
#pragma unroll
    for (int nt = 0; nt < 4; ++nt) {
      int boff = (ks * 32 + bn * 16 + wave * 4 + nt) * 64 + lane;
      short8 bh = Bh8[boff];
      short8 bl = Bl8[boff];
#pragma unroll
      for (int mt = 0; mt < 4; ++mt) {
        acc[mt][nt] = __builtin_amdgcn_mfma_f32_16x16x32_bf16(ah[mt], bh, acc[mt][nt], 0, 0, 0);
        acc[mt][nt] = __builtin_amdgcn_mfma_f32_16x16x32_bf16(alo[mt], bh, acc[mt][nt], 0, 0, 0);
        acc[mt][nt] = __builtin_amdgcn_mfma_f32_16x16x32_bf16(ah[mt], bl, acc[mt][nt], 0, 0, 0);
      }
    }
    __syncthreads();
  }
  // epilogue: C/D layout col=lane&15, row=(lane>>4)*4+reg
  const int colq = lane & 15, quad = lane >> 4;
  if (bn == 0) {
#pragma unroll
    for (int mt = 0; mt < 4; ++mt)
#pragma unroll
      for (int reg = 0; reg < 4; ++reg) {
        int rr = row0 + mt * 16 + quad * 4 + reg;
        if (rr < NN) {
#pragma unroll
          for (int nt = 0; nt < 4; ++nt)
            ylbf[rr * IC + wave * 64 + nt * 16 + colq] = f2bf(acc[mt][nt][reg]);
        }
      }
  } else {
    const int head = wave;
    float asv[4], adv[4];
#pragma unroll
    for (int j = 0; j < 4; ++j) {
      asv[j] = asrc[head * 64 + j * 16 + colq];
      adv[j] = adst[head * 64 + j * 16 + colq];
    }
#pragma unroll
    for (int mt = 0; mt < 4; ++mt)
#pragma unroll
      for (int reg = 0; reg < 4; ++reg) {
        int rr = row0 + mt * 16 + quad * 4 + reg;
        float sA = 0.f, dA = 0.f;
#pragma unroll
        for (int j = 0; j < 4; ++j) {
          float hA = acc[mt][j][reg];
          sA = fmaf(hA, asv[j], sA);
          dA = fmaf(hA, adv[j], dA);
          if (rr < NN) hbf[rr * IC + head * 64 + j * 16 + colq] = f2bf(hA);
        }
#pragma unroll
        for (int off = 1; off < 16; off <<= 1) {
          sA += __shfl_xor(sA, off, 64);
          dA += __shfl_xor(dA, off, 64);
        }
        if (rr < NN) {
          if (colq == 0) als[rr * 4 + head] = sA;
          else if (colq == 1) ald[rr * 4 + head] = dA;
        }
      }
  }
}

// ---------------- single-kernel scan: each block computes its own global prefix ---
// block 0 also zeroes S1/S2 for layer-2 reuse (k_gemm consumed them already)
__global__ __launch_bounds__(1024) void k_scan(const int* __restrict__ counts,
                                               int* __restrict__ start,
                                               int* __restrict__ cursor,
                                               float* __restrict__ S1,
                                               float* __restrict__ S2) {
  __shared__ int red[16];
  __shared__ int buf[1024];
  const int tid = threadIdx.x, b = blockIdx.x;
  const int base = b * 1024;
  // phase 1: prefix = sum of counts[0, base)
  int pre = 0;
  for (int i = tid; i < base; i += 1024) pre += counts[i];
#pragma unroll
  for (int off = 1; off < 64; off <<= 1) pre += __shfl_xor(pre, off, 64);
  if ((tid & 63) == 0) red[tid >> 6] = pre;
  if (b == 0 && tid < 256) {
    S1[tid] = 0.f;
    S2[tid] = 0.f;
  }
  __syncthreads();
  int bpre = 0;
#pragma unroll
  for (int w = 0; w < 16; ++w) bpre += red[w];
  // phase 2: local inclusive scan of this block's chunk
  int i = base + tid;
  int v = (i < NN) ? counts[i] : 0;
  buf[tid] = v;
  __syncthreads();
  for (int off = 1; off < 1024; off <<= 1) {
    int t = (tid >= off) ? buf[tid - off] : 0;
    __syncthreads();
    buf[tid] += t;
    __syncthreads();
  }
  if (i < NN) {
    int s = bpre + buf[tid] - v;
    start[i] = s;
    cursor[i] = s;
  }
  if (b == 48 && tid == 1023) start[NN] = bpre + buf[1023];
}

__global__ __launch_bounds__(256) void k_scatter(const int* __restrict__ src,
                                                 const int* __restrict__ dst,
                                                 int* __restrict__ cursor,
                                                 int* __restrict__ srcs) {
  int e = blockIdx.x * 256 + threadIdx.x;
  int pos = atomicAdd(&cursor[dst[e]], 1);
  srcs[pos] = src[e];
}

// ---------------- layer-1 aggregation: wave/node; no-max softmax; p in LDS -------
__global__ __launch_bounds__(256) void k_agg(const ushort4* __restrict__ hq,
                                             ushort4* __restrict__ x1,
                                             const float4* __restrict__ als4,
                                             const float4* __restrict__ ald4,
                                             const int* __restrict__ start,
                                             const int* __restrict__ srcs,
                                             const float4* __restrict__ lb4,
                                             const float4* __restrict__ cb4) {
  __shared__ float lsp[1024];          // per-edge p: [wave][edge j][head]
  const int tid = threadIdx.x;
  const int wave = tid >> 6, lane = tid & 63, head = lane >> 4;
  const int n = blockIdx.x * 4 + wave;
  const float* als = (const float*)als4;
  const int s = start[n], t = start[n + 1];
  const int deg = t - s;
  const float4 aldv = ald4[n];
  int svk = -1;
  float p0 = 0.f, p1 = 0.f, p2 = 0.f, p3 = 0.f;
  if (lane < deg) {
    svk = srcs[s + lane];
    float4 a = als4[svk];
    p0 = __expf(lrelu(a.x + aldv.x));
    p1 = __expf(lrelu(a.y + aldv.y));
    p2 = __expf(lrelu(a.z + aldv.z));
    p3 = __expf(lrelu(a.w + aldv.w));
  }
  *(float4*)&lsp[wave * 256 + lane * 4] = make_float4(p0, p1, p2, p3);
  float d0 = p0, d1 = p1, d2 = p2, d3 = p3;
  const float aldh = head == 0 ? aldv.x : head == 1 ? aldv.y : head == 2 ? aldv.z : aldv.w;
  if (deg > 64) {
    for (int i = s + 64 + lane; i < t; i += 64) {
      float4 a = als4[srcs[i]];
      d0 += __expf(lrelu(a.x + aldv.x));
      d1 += __expf(lrelu(a.y + aldv.y));
      d2 += __expf(lrelu(a.z + aldv.z));
      d3 += __expf(lrelu(a.w + aldv.w));
    }
  }
#pragma unroll
  for (int off = 1; off < 64; off <<= 1) {
    d0 += __shfl_xor(d0, off, 64);
    d1 += __shfl_xor(d1, off, 64);
    d2 += __shfl_xor(d2, off, 64);
    d3 += __shfl_xor(d3, off, 64);
  }
  const float inv =
      1.f / ((head == 0 ? d0 : head == 1 ? d1 : head == 2 ? d2 : d3) + 1e-16f);
  // pass 2: 4x-unrolled weighted gather
  float a0 = 0.f, a1 = 0.f, a2 = 0.f, a3 = 0.f;
  const int cnt = min(deg, 64);
  const int wbase = wave * 256 + head;
  int j = 0;
  for (; j + 4 <= cnt; j += 4) {
    int sv0 = __shfl(svk, j, 64), sv1 = __shfl(svk, j + 1, 64);
    int sv2 = __shfl(svk, j + 2, 64), sv3 = __shfl(svk, j + 3, 64);
    ushort4 hv0 = hq[sv0 * 64 + lane];
    ushort4 hv1 = hq[sv1 * 64 + lane];
    ushort4 hv2 = hq[sv2 * 64 + lane];
    ushort4 hv3 = hq[sv3 * 64 + lane];
    float w0 = lsp[wbase + j * 4], w1 = lsp[wbase + j * 4 + 4];
    float w2 = lsp[wbase + j * 4 + 8], w3 = lsp[wbase + j * 4 + 12];
    a0 = fmaf(w0, b2f(hv0.x), a0); a1 = fmaf(w0, b2f(hv0.y), a1);
    a2 = fmaf(w0, b2f(hv0.z), a2); a3 = fmaf(w0, b2f(hv0.w), a3);
    a0 = fmaf(w1, b2f(hv1.x), a0); a1 = fmaf(w1, b2f(hv1.y), a1);
    a2 = fmaf(w1, b2f(hv1.z), a2); a3 = fmaf(w1, b2f(hv1.w), a3);
    a0 = fmaf(w2, b2f(hv2.x), a0); a1 = fmaf(w2, b2f(hv2.y), a1);
    a2 = fmaf(w2, b2f(hv2.z), a2); a3 = fmaf(w2, b2f(hv2.w), a3);
    a0 = fmaf(w3, b2f(hv3.x), a0); a1 = fmaf(w3, b2f(hv3.y), a1);
    a2 = fmaf(w3, b2f(hv3.z), a2); a3 = fmaf(w3, b2f(hv3.w), a3);
  }
  for (; j < cnt; ++j) {
    int sv = __shfl(svk, j, 64);
    float w = lsp[wbase + j * 4];
    ushort4 hv = hq[sv * 64 + lane];
    a0 = fmaf(w, b2f(hv.x), a0);
    a1 = fmaf(w, b2f(hv.y), a1);
    a2 = fmaf(w, b2f(hv.z), a2);
    a3 = fmaf(w, b2f(hv.w), a3);
  }
  if (deg > 64) {
    for (int i = s + 64; i < t; ++i) {
      int sv = srcs[i];
      float av = als[sv * 4 + head];
      float p = __expf(lrelu(av + aldh));
      ushort4 hv = hq[sv * 64 + lane];
      a0 = fmaf(p, b2f(hv.x), a0);
      a1 = fmaf(p, b2f(hv.y), a1);
      a2 = fmaf(p, b2f(hv.z), a2);
      a3 = fmaf(p, b2f(hv.w), a3);
    }
  }
  // epilogue: skip + biases + relu -> bf16 x1
  ushort4 yb = x1[n * 64 + lane];
  float4 bb1 = lb4[lane], bb2 = cb4[lane];
  ushort4 rb;
  rb.x = f2bf(fmaxf(fmaf(a0, inv, b2f(yb.x) + bb1.x + bb2.x), 0.f));
  rb.y = f2bf(fmaxf(fmaf(a1, inv, b2f(yb.y) + bb1.y + bb2.y), 0.f));
  rb.z = f2bf(fmaxf(fmaf(a2, inv, b2f(yb.z) + bb1.z + bb2.z), 0.f));
  rb.w = f2bf(fmaxf(fmaf(a3, inv, b2f(yb.w) + bb1.w + bb2.w), 0.f));
  x1[n * 64 + lane] = rb;
}

// ---------------- layer 2 node kernel: inline BN-finalize + projections ----------
__global__ __launch_bounds__(256) void k_node2(const ushort4* __restrict__ x1,
                                               const float* __restrict__ S1,
                                               const float* __restrict__ S2,
                                               const float* __restrict__ g3,
                                               const float* __restrict__ b3,
                                               const float4* __restrict__ Wl4,
                                               const float4* __restrict__ Wc4,
                                               const float* __restrict__ a3s,
                                               const float* __restrict__ a3d,
                                               const float* __restrict__ l3b,
                                               const float* __restrict__ c3b,
                                               float2* __restrict__ y32,
                                               float4* __restrict__ nd4) {
  __shared__ float sc[256], sh[256];
  const int tid = threadIdx.x;
  {
    float mu = S1[tid] * (1.f / NN);
    float var = S2[tid] * (1.f / NN) - mu * mu;
    float ss = g3[tid] / sqrtf(var + EPS);
    sc[tid] = ss;
    sh[tid] = b3[tid] - mu * ss;
  }
  __syncthreads();
  const int n = blockIdx.x * 4 + (tid >> 6);
  const int lane = tid & 63;
  ushort4 xb = x1[n * 64 + lane];
  float x0 = fmaf(b2f(xb.x), sc[lane * 4 + 0], sh[lane * 4 + 0]);
  float x1v = fmaf(b2f(xb.y), sc[lane * 4 + 1], sh[lane * 4 + 1]);
  float x2 = fmaf(b2f(xb.z), sc[lane * 4 + 2], sh[lane * 4 + 2]);
  float x3 = fmaf(b2f(xb.w), sc[lane * 4 + 3], sh[lane * 4 + 3]);
  float4 wa = Wl4[lane * 2], wb = Wl4[lane * 2 + 1];
  float y0 = x0 * wa.x + x1v * wa.z + x2 * wb.x + x3 * wb.z;
  float y1 = x0 * wa.y + x1v * wa.w + x2 * wb.y + x3 * wb.w;
  float4 ca = Wc4[lane * 2], cb = Wc4[lane * 2 + 1];
  float g0 = x0 * ca.x + x1v * ca.z + x2 * cb.x + x3 * cb.z;
  float g1 = x0 * ca.y + x1v * ca.w + x2 * cb.y + x3 * cb.w;
#pragma unroll
  for (int off = 1; off < 64; off <<= 1) {
    y0 += __shfl_xor(y0, off, 64);
    y1 += __shfl_xor(y1, off, 64);
    g0 += __shfl_xor(g0, off, 64);
    g1 += __shfl_xor(g1, off, 64);
  }
  if (lane == 0) {
    y32[n] = make_float2(y0 + l3b[0] + c3b[0], y1 + l3b[1] + c3b[1]);
    nd4[n] = make_float4(g0 * a3s[0] + g1 * a3s[1], g0, g1,
                         g0 * a3d[0] + g1 * a3d[1]);
  }
}

// ---------------- layer 2 softmax-aggregate + output, single pass ----------------
__global__ __launch_bounds__(256) void k_final(const int* __restrict__ start,
                                               const int* __restrict__ srcs,
                                               const float4* __restrict__ nd4,
                                               const float2* __restrict__ y32,
                                               float* __restrict__ out) {
  const int tid = threadIdx.x;
  const int n = blockIdx.x * 16 + (tid >> 4);
  const int li = tid & 15;
  const int s = start[n], t = start[n + 1];
  const float ad = nd4[n].w;
  float den = 0.f, a0 = 0.f, a1 = 0.f;
  for (int ii = s + li; ii < t; ii += 16) {
    float4 vv = nd4[srcs[ii]];
    float p = __expf(lrelu(vv.x + ad));
    den += p;
    a0 = fmaf(p, vv.y, a0);
    a1 = fmaf(p, vv.z, a1);
  }
#pragma unroll
  for (int off = 1; off < 16; off <<= 1) {
    den += __shfl_xor(den, off, 64);
    a0 += __shfl_xor(a0, off, 64);
    a1 += __shfl_xor(a1, off, 64);
  }
  if (li == 0) {
    float2 y = y32[n];
    float inv = 1.f / (den + 1e-16f);
    out[2 * n] = fmaxf(fmaf(a0, inv, y.x), 0.f);
    out[2 * n + 1] = fmaxf(fmaf(a1, inv, y.y), 0.f);
  }
}

extern "C" void kernel_launch(void* const* d_in, const int* in_sizes, int n_in,
                              void* d_out, int out_size, void* d_ws, size_t ws_size,
                              hipStream_t stream) {
  const float* x = (const float*)d_in[0];
  const int* ei = (const int*)d_in[1];
  const float* bn1_g = (const float*)d_in[2];
  const float* bn1_b = (const float*)d_in[3];
  const float* lin1_W = (const float*)d_in[4];
  const float* lin1_b = (const float*)d_in[5];
  const float* con1_W = (const float*)d_in[6];
  const float* con1_as = (const float*)d_in[7];
  const float* con1_ad = (const float*)d_in[8];
  const float* con1_b = (const float*)d_in[9];
  const float* bn3_g = (const float*)d_in[10];
  const float* bn3_b = (const float*)d_in[11];
  const float* lin3_W = (const float*)d_in[12];
  const float* lin3_b = (const float*)d_in[13];
  const float* con3_W = (const float*)d_in[14];
  const float* con3_as = (const float*)d_in[15];
  const float* con3_ad = (const float*)d_in[16];
  const float* con3_b = (const float*)d_in[17];
  float* ws = (float*)d_ws;
  const int* srcA = ei;
  const int* dstA = ei + NE;

  float* S1 = ws + OFF_S1;
  float* S2 = ws + OFF_S2;
  int* counts = (int*)(ws + OFF_COUNTS);
  int* cursor = (int*)(ws + OFF_CURSOR);
  int* start = (int*)(ws + OFF_START);
  float* als = ws + OFF_ALS;
  float* ald = ws + OFF_ALD;
  int* srcs = (int*)(ws + OFF_SRCS);
  float2* y32 = (float2*)(ws + OFF_Y32);
  float4* nd4 = (float4*)(ws + OFF_ND4);
  unsigned short* Bfh = (unsigned short*)(ws + OFF_BFH);
  unsigned short* Bfl = (unsigned short*)(ws + OFF_BFL);
  unsigned short* hbf = (unsigned short*)(ws + OFF_HBF);
  unsigned short* ylbf = (unsigned short*)(ws + OFF_YLBF);  // becomes x1 in place

  hipMemsetAsync(ws, 0, (size_t)ZERO_END * sizeof(float), stream);

  k_prep<<<4661, 256, 0, stream>>>(x, S1, S2, dstA, counts, lin1_W, con1_W, Bfh,
                                   Bfl);
  k_gemm<<<dim3(2, 782), 256, 0, stream>>>(x, S1, S2, bn1_g, bn1_b, Bfh, Bfl, ylbf,
                                           hbf, con1_as, con1_ad, als, ald);
  k_scan<<<49, 1024, 0, stream>>>(counts, start, cursor, S1, S2);
  k_scatter<<<3125, 256, 0, stream>>>(srcA, dstA, cursor, srcs);
  k_agg<<<12500, 256, 0, stream>>>((const ushort4*)hbf, (ushort4*)ylbf,
                                   (const float4*)als, (const float4*)ald, start,
                                   srcs, (const float4*)lin1_b,
                                   (const float4*)con1_b);
  k_bnstats2<<<1024, 256, 0, stream>>>(ylbf, S1, S2);
  k_node2<<<12500, 256, 0, stream>>>((const ushort4*)ylbf, S1, S2, bn3_g, bn3_b,
                                     (const float4*)lin3_W, (const float4*)con3_W,
                                     con3_as, con3_ad, lin3_b, con3_b, y32, nd4);
  k_final<<<3125, 256, 0, stream>>>(start, srcs, nd4, y32, (float*)d_out);
}

// Round 9
// 411.695 us; speedup vs baseline: 1.0654x; 1.0654x over previous
//
#include <hip/hip_runtime.h>
#include <math.h>

#define NN 50000
#define NE 800000
#define IC 256
#define EPS 1e-5f

typedef __attribute__((ext_vector_type(8))) short short8;   // 8 bf16 (4 VGPRs)
typedef __attribute__((ext_vector_type(4))) float f32x4;    // MFMA acc

// ---------------- ws layout (float offsets) ----------------
enum : int {
  OFF_S1     = 0,                        // [256] zeroed
  OFF_S2     = 256,                      // [256] zeroed
  OFF_COUNTS = 512,                      // int[NN] zeroed
  ZERO_END   = OFF_COUNTS + 50000,       // 50512
  OFF_CURSOR = ZERO_END,                 // int[NN]
  OFF_START  = OFF_CURSOR + 50000,       // int[NN+1] pad 50004
  OFF_BSUM   = OFF_START + 50004,        // int[64] (unused, keep layout)
  OFF_BOFF   = OFF_BSUM + 64,            // int[64] (unused, keep layout)
  OFF_ALS    = OFF_BOFF + 64,            // [NN*4] (16B aligned)
  OFF_ALD    = OFF_ALS + 200000,
  OFF_SRCS   = OFF_ALD + 200000,         // int[NE]
  OFF_Y32    = OFF_SRCS + 800000,        // float2[NN]
  OFF_ND4    = OFF_Y32 + 100000,         // float4[NN] = (al3s, h3x, h3y, al3d)
  OFF_BFH    = OFF_ND4 + 200000,         // ushort[131072]
  OFF_HBF    = OFF_BFH + 65536,          // ushort[NN*256]
  OFF_YLBF   = OFF_HBF + 6400000,        // ushort[NN*256]; becomes x1 in place
  WS_FLOATS  = OFF_YLBF + 6400000        // ~58 MB
};

__device__ __forceinline__ float lrelu(float s) { return s > 0.f ? s : 0.2f * s; }
__device__ __forceinline__ float b2f(unsigned short u) {
  return __uint_as_float(((unsigned)u) << 16);
}
__device__ __forceinline__ unsigned short f2bf(float f) {  // RNE
  unsigned u = __float_as_uint(f);
  return (unsigned short)((u + 0x7fffu + ((u >> 16) & 1u)) >> 16);
}

// ---------------- fused prologue: BN1 stats | edge histogram | weight prep -------
// blocks [0,1024): column sums of x; [1024,4149): dst histogram; [4149,4661): prepB
__global__ __launch_bounds__(256) void k_prep(const float* __restrict__ x,
                                              float* __restrict__ S1,
                                              float* __restrict__ S2,
                                              const int* __restrict__ dst,
                                              int* __restrict__ counts,
                                              const float* __restrict__ Wlin,
                                              const float* __restrict__ Wcon,
                                              unsigned short* __restrict__ Bfh) {
  int b = blockIdx.x;
  if (b < 1024) {
    int c = threadIdx.x;
    float s1 = 0.f, s2 = 0.f;
    for (int r = b; r < NN; r += 1024) {
      float v = x[r * IC + c];
      s1 += v;
      s2 = fmaf(v, v, s2);
    }
    atomicAdd(&S1[c], s1);
    atomicAdd(&S2[c], s2);
  } else if (b < 4149) {
    int e = (b - 1024) * 256 + threadIdx.x;  // exactly NE
    atomicAdd(&counts[dst[e]], 1);
  } else {
    int id = (b - 4149) * 256 + threadIdx.x;  // < 131072
    int j = id & 7, lane = (id >> 3) & 63, nt = (id >> 9) & 31, ks = id >> 14;
    int k = ks * 32 + ((lane >> 4) << 3) + j;
    int n = nt * 16 + (lane & 15);
    float v = (n < 256) ? Wlin[k * 256 + n] : Wcon[k * 256 + (n - 256)];
    Bfh[id] = f2bf(v);
  }
}

// ---------------- BN stats (layer 2, bf16 input) ----------------
__global__ __launch_bounds__(256) void k_bnstats2(const unsigned short* __restrict__ x1,
                                                  float* __restrict__ S1,
                                                  float* __restrict__ S2) {
  int c = threadIdx.x;
  float s1 = 0.f, s2 = 0.f;
  for (int r = blockIdx.x; r < NN; r += gridDim.x) {
    float v = b2f(x1[r * IC + c]);
    s1 += v;
    s2 = fmaf(v, v, s2);
  }
  atomicAdd(&S1[c], s1);
  atomicAdd(&S2[c], s2);
}

// ---------------- MFMA dual GEMM (single bf16 chain), fused BN + alpha ----------
// grid (2, 782): block = 64 rows x 256 cols. bn=0 -> ylbf, bn=1 -> hbf + logits.
__global__ __launch_bounds__(256, 4) void k_gemm(const float* __restrict__ x,
                                                 const float* __restrict__ S1,
                                                 const float* __restrict__ S2,
                                                 const float* __restrict__ bng,
                                                 const float* __restrict__ bnb,
                                                 const unsigned short* __restrict__ Bfh,
                                                 unsigned short* __restrict__ ylbf,
                                                 unsigned short* __restrict__ hbf,
                                                 const float* __restrict__ asrc,
                                                 const float* __restrict__ adst,
                                                 float* __restrict__ als,
                                                 float* __restrict__ ald) {
  __shared__ unsigned short Ah[2048];
  __shared__ float sc[256], sh[256];
  const int tid = threadIdx.x;
  const int bn = blockIdx.x;
  const int row0 = blockIdx.y * 64;
  const int wave = tid >> 6, lane = tid & 63;
  {
    float mu = S1[tid] * (1.f / NN);
    float var = S2[tid] * (1.f / NN) - mu * mu;
    float ss = bng[tid] / sqrtf(var + EPS);
    sc[tid] = ss;
    sh[tid] = bnb[tid] - mu * ss;
  }
  const float4* x4 = (const float4*)x;
  const short8* Bh8 = (const short8*)Bfh;
  f32x4 acc[4][4];
#pragma unroll
  for (int i = 0; i < 4; ++i)
#pragma unroll
    for (int j = 0; j < 4; ++j) acc[i][j] = (f32x4){0.f, 0.f, 0.f, 0.f};

  const int m = tid >> 2, kg = tid & 3;
  const int r = row0 + m;
  const int aaddr = (((m >> 4) * 64) + ((m & 15) | (kg << 4))) * 8;
  __syncthreads();

  for (int ks = 0; ks < 8; ++ks) {
    const int c0 = ks * 32 + kg * 8;
    float v[8];
    if (r < NN) {
      int base = (r * IC + c0) >> 2;
      float4 fa = x4[base], fb = x4[base + 1];
      v[0] = fa.x; v[1] = fa.y; v[2] = fa.z; v[3] = fa.w;
      v[4] = fb.x; v[5] = fb.y; v[6] = fb.z; v[7] = fb.w;
#pragma unroll
      for (int j = 0; j < 8; ++j) v[j] = fmaf(v[j], sc[c0 + j], sh[c0 + j]);
    } else {
#pragma unroll
      for (int j = 0; j < 8; ++j) v[j] = 0.f;
    }
    unsigned ph[4];
#pragma unroll
    for (int j = 0; j < 4; ++j) {
      ph[j] = (unsigned)f2bf(v[2 * j]) | ((unsigned)f2bf(v[2 * j + 1]) << 16);
    }
    *(uint4*)&Ah[aaddr] = make_uint4(ph[0], ph[1], ph[2], ph[3]);
    __syncthreads();

    short8 ah[4];
#pragma unroll
    for (int mt = 0; mt < 4; ++mt)
      ah[mt] = *(const short8*)&Ah[(mt * 64 + lane) * 8];
#pragma unroll
    for (int nt = 0; nt < 4; ++nt) {
      short8 bh = Bh8[(ks * 32 + bn * 16 + wave * 4 + nt) * 64 + lane];
#pragma unroll
      for (int mt = 0; mt < 4; ++mt)
        acc[mt][nt] = __builtin_amdgcn_mfma_f32_16x16x32_bf16(ah[mt], bh, acc[mt][nt], 0, 0, 0);
    }
    __syncthreads();
  }
  // epilogue: C/D layout col=lane&15, row=(lane>>4)*4+reg
  const int colq = lane & 15, quad = lane >> 4;
  if (bn == 0) {
#pragma unroll
    for (int mt = 0; mt < 4; ++mt)
#pragma unroll
      for (int reg = 0; reg < 4; ++reg) {
        int rr = row0 + mt * 16 + quad * 4 + reg;
        if (rr < NN) {
#pragma unroll
          for (int nt = 0; nt < 4; ++nt)
            ylbf[rr * IC + wave * 64 + nt * 16 + colq] = f2bf(acc[mt][nt][reg]);
        }
      }
  } else {
    const int head = wave;
    float asv[4], adv[4];
#pragma unroll
    for (int j = 0; j < 4; ++j) {
      asv[j] = asrc[head * 64 + j * 16 + colq];
      adv[j] = adst[head * 64 + j * 16 + colq];
    }
#pragma unroll
    for (int mt = 0; mt < 4; ++mt)
#pragma unroll
      for (int reg = 0; reg < 4; ++reg) {
        int rr = row0 + mt * 16 + quad * 4 + reg;
        float sA = 0.f, dA = 0.f;
#pragma unroll
        for (int j = 0; j < 4; ++j) {
          float hA = acc[mt][j][reg];
          sA = fmaf(hA, asv[j], sA);
          dA = fmaf(hA, adv[j], dA);
          if (rr < NN) hbf[rr * IC + head * 64 + j * 16 + colq] = f2bf(hA);
        }
#pragma unroll
        for (int off = 1; off < 16; off <<= 1) {
          sA += __shfl_xor(sA, off, 64);
          dA += __shfl_xor(dA, off, 64);
        }
        if (rr < NN) {
          if (colq == 0) als[rr * 4 + head] = sA;
          else if (colq == 1) ald[rr * 4 + head] = dA;
        }
      }
  }
}

// ---------------- single-kernel scan: each block computes its own global prefix ---
// block 0 also zeroes S1/S2 for layer-2 reuse (k_gemm consumed them already)
__global__ __launch_bounds__(1024) void k_scan(const int* __restrict__ counts,
                                               int* __restrict__ start,
                                               int* __restrict__ cursor,
                                               float* __restrict__ S1,
                                               float* __restrict__ S2) {
  __shared__ int red[16];
  __shared__ int buf[1024];
  const int tid = threadIdx.x, b = blockIdx.x;
  const int base = b * 1024;
  int pre = 0;
  for (int i = tid; i < base; i += 1024) pre += counts[i];
#pragma unroll
  for (int off = 1; off < 64; off <<= 1) pre += __shfl_xor(pre, off, 64);
  if ((tid & 63) == 0) red[tid >> 6] = pre;
  if (b == 0 && tid < 256) {
    S1[tid] = 0.f;
    S2[tid] = 0.f;
  }
  __syncthreads();
  int bpre = 0;
#pragma unroll
  for (int w = 0; w < 16; ++w) bpre += red[w];
  int i = base + tid;
  int v = (i < NN) ? counts[i] : 0;
  buf[tid] = v;
  __syncthreads();
  for (int off = 1; off < 1024; off <<= 1) {
    int t = (tid >= off) ? buf[tid - off] : 0;
    __syncthreads();
    buf[tid] += t;
    __syncthreads();
  }
  if (i < NN) {
    int s = bpre + buf[tid] - v;
    start[i] = s;
    cursor[i] = s;
  }
  if (b == 48 && tid == 1023) start[NN] = bpre + buf[1023];
}

__global__ __launch_bounds__(256) void k_scatter(const int* __restrict__ src,
                                                 const int* __restrict__ dst,
                                                 int* __restrict__ cursor,
                                                 int* __restrict__ srcs) {
  int e = blockIdx.x * 256 + threadIdx.x;
  int pos = atomicAdd(&cursor[dst[e]], 1);
  srcs[pos] = src[e];
}

// ---------------- layer-1 aggregation: wave/node; no-max softmax; p in LDS -------
__global__ __launch_bounds__(256) void k_agg(const ushort4* __restrict__ hq,
                                             ushort4* __restrict__ x1,
                                             const float4* __restrict__ als4,
                                             const float4* __restrict__ ald4,
                                             const int* __restrict__ start,
                                             const int* __restrict__ srcs,
                                             const float4* __restrict__ lb4,
                                             const float4* __restrict__ cb4) {
  __shared__ float lsp[1024];          // per-edge p: [wave][edge j][head]
  const int tid = threadIdx.x;
  const int wave = tid >> 6, lane = tid & 63, head = lane >> 4;
  const int n = blockIdx.x * 4 + wave;
  const float* als = (const float*)als4;
  const int s = start[n], t = start[n + 1];
  const int deg = t - s;
  const float4 aldv = ald4[n];
  int svk = -1;
  float p0 = 0.f, p1 = 0.f, p2 = 0.f, p3 = 0.f;
  if (lane < deg) {
    svk = srcs[s + lane];
    float4 a = als4[svk];
    p0 = __expf(lrelu(a.x + aldv.x));
    p1 = __expf(lrelu(a.y + aldv.y));
    p2 = __expf(lrelu(a.z + aldv.z));
    p3 = __expf(lrelu(a.w + aldv.w));
  }
  *(float4*)&lsp[wave * 256 + lane * 4] = make_float4(p0, p1, p2, p3);
  float d0 = p0, d1 = p1, d2 = p2, d3 = p3;
  const float aldh = head == 0 ? aldv.x : head == 1 ? aldv.y : head == 2 ? aldv.z : aldv.w;
  if (deg > 64) {
    for (int i = s + 64 + lane; i < t; i += 64) {
      float4 a = als4[srcs[i]];
      d0 += __expf(lrelu(a.x + aldv.x));
      d1 += __expf(lrelu(a.y + aldv.y));
      d2 += __expf(lrelu(a.z + aldv.z));
      d3 += __expf(lrelu(a.w + aldv.w));
    }
  }
#pragma unroll
  for (int off = 1; off < 64; off <<= 1) {
    d0 += __shfl_xor(d0, off, 64);
    d1 += __shfl_xor(d1, off, 64);
    d2 += __shfl_xor(d2, off, 64);
    d3 += __shfl_xor(d3, off, 64);
  }
  const float inv =
      1.f / ((head == 0 ? d0 : head == 1 ? d1 : head == 2 ? d2 : d3) + 1e-16f);
  // pass 2: 4x-unrolled weighted gather
  float a0 = 0.f, a1 = 0.f, a2 = 0.f, a3 = 0.f;
  const int cnt = min(deg, 64);
  const int wbase = wave * 256 + head;
  int j = 0;
  for (; j + 4 <= cnt; j += 4) {
    int sv0 = __shfl(svk, j, 64), sv1 = __shfl(svk, j + 1, 64);
    int sv2 = __shfl(svk, j + 2, 64), sv3 = __shfl(svk, j + 3, 64);
    ushort4 hv0 = hq[sv0 * 64 + lane];
    ushort4 hv1 = hq[sv1 * 64 + lane];
    ushort4 hv2 = hq[sv2 * 64 + lane];
    ushort4 hv3 = hq[sv3 * 64 + lane];
    float w0 = lsp[wbase + j * 4], w1 = lsp[wbase + j * 4 + 4];
    float w2 = lsp[wbase + j * 4 + 8], w3 = lsp[wbase + j * 4 + 12];
    a0 = fmaf(w0, b2f(hv0.x), a0); a1 = fmaf(w0, b2f(hv0.y), a1);
    a2 = fmaf(w0, b2f(hv0.z), a2); a3 = fmaf(w0, b2f(hv0.w), a3);
    a0 = fmaf(w1, b2f(hv1.x), a0); a1 = fmaf(w1, b2f(hv1.y), a1);
    a2 = fmaf(w1, b2f(hv1.z), a2); a3 = fmaf(w1, b2f(hv1.w), a3);
    a0 = fmaf(w2, b2f(hv2.x), a0); a1 = fmaf(w2, b2f(hv2.y), a1);
    a2 = fmaf(w2, b2f(hv2.z), a2); a3 = fmaf(w2, b2f(hv2.w), a3);
    a0 = fmaf(w3, b2f(hv3.x), a0); a1 = fmaf(w3, b2f(hv3.y), a1);
    a2 = fmaf(w3, b2f(hv3.z), a2); a3 = fmaf(w3, b2f(hv3.w), a3);
  }
  for (; j < cnt; ++j) {
    int sv = __shfl(svk, j, 64);
    float w = lsp[wbase + j * 4];
    ushort4 hv = hq[sv * 64 + lane];
    a0 = fmaf(w, b2f(hv.x), a0);
    a1 = fmaf(w, b2f(hv.y), a1);
    a2 = fmaf(w, b2f(hv.z), a2);
    a3 = fmaf(w, b2f(hv.w), a3);
  }
  if (deg > 64) {
    for (int i = s + 64; i < t; ++i) {
      int sv = srcs[i];
      float av = als[sv * 4 + head];
      float p = __expf(lrelu(av + aldh));
      ushort4 hv = hq[sv * 64 + lane];
      a0 = fmaf(p, b2f(hv.x), a0);
      a1 = fmaf(p, b2f(hv.y), a1);
      a2 = fmaf(p, b2f(hv.z), a2);
      a3 = fmaf(p, b2f(hv.w), a3);
    }
  }
  // epilogue: skip + biases + relu -> bf16 x1
  ushort4 yb = x1[n * 64 + lane];
  float4 bb1 = lb4[lane], bb2 = cb4[lane];
  ushort4 rb;
  rb.x = f2bf(fmaxf(fmaf(a0, inv, b2f(yb.x) + bb1.x + bb2.x), 0.f));
  rb.y = f2bf(fmaxf(fmaf(a1, inv, b2f(yb.y) + bb1.y + bb2.y), 0.f));
  rb.z = f2bf(fmaxf(fmaf(a2, inv, b2f(yb.z) + bb1.z + bb2.z), 0.f));
  rb.w = f2bf(fmaxf(fmaf(a3, inv, b2f(yb.w) + bb1.w + bb2.w), 0.f));
  x1[n * 64 + lane] = rb;
}

// ---------------- layer 2 node kernel: inline BN-finalize + projections ----------
__global__ __launch_bounds__(256) void k_node2(const ushort4* __restrict__ x1,
                                               const float* __restrict__ S1,
                                               const float* __restrict__ S2,
                                               const float* __restrict__ g3,
                                               const float* __restrict__ b3,
                                               const float4* __restrict__ Wl4,
                                               const float4* __restrict__ Wc4,
                                               const float* __restrict__ a3s,
                                               const float* __restrict__ a3d,
                                               const float* __restrict__ l3b,
                                               const float* __restrict__ c3b,
                                               float2* __restrict__ y32,
                                               float4* __restrict__ nd4) {
  __shared__ float sc[256], sh[256];
  const int tid = threadIdx.x;
  {
    float mu = S1[tid] * (1.f / NN);
    float var = S2[tid] * (1.f / NN) - mu * mu;
    float ss = g3[tid] / sqrtf(var + EPS);
    sc[tid] = ss;
    sh[tid] = b3[tid] - mu * ss;
  }
  __syncthreads();
  const int n = blockIdx.x * 4 + (tid >> 6);
  const int lane = tid & 63;
  ushort4 xb = x1[n * 64 + lane];
  float x0 = fmaf(b2f(xb.x), sc[lane * 4 + 0], sh[lane * 4 + 0]);
  float x1v = fmaf(b2f(xb.y), sc[lane * 4 + 1], sh[lane * 4 + 1]);
  float x2 = fmaf(b2f(xb.z), sc[lane * 4 + 2], sh[lane * 4 + 2]);
  float x3 = fmaf(b2f(xb.w), sc[lane * 4 + 3], sh[lane * 4 + 3]);
  float4 wa = Wl4[lane * 2], wb = Wl4[lane * 2 + 1];
  float y0 = x0 * wa.x + x1v * wa.z + x2 * wb.x + x3 * wb.z;
  float y1 = x0 * wa.y + x1v * wa.w + x2 * wb.y + x3 * wb.w;
  float4 ca = Wc4[lane * 2], cb = Wc4[lane * 2 + 1];
  float g0 = x0 * ca.x + x1v * ca.z + x2 * cb.x + x3 * cb.z;
  float g1 = x0 * ca.y + x1v * ca.w + x2 * cb.y + x3 * cb.w;
#pragma unroll
  for (int off = 1; off < 64; off <<= 1) {
    y0 += __shfl_xor(y0, off, 64);
    y1 += __shfl_xor(y1, off, 64);
    g0 += __shfl_xor(g0, off, 64);
    g1 += __shfl_xor(g1, off, 64);
  }
  if (lane == 0) {
    y32[n] = make_float2(y0 + l3b[0] + c3b[0], y1 + l3b[1] + c3b[1]);
    nd4[n] = make_float4(g0 * a3s[0] + g1 * a3s[1], g0, g1,
                         g0 * a3d[0] + g1 * a3d[1]);
  }
}

// ---------------- layer 2 softmax-aggregate + output, single pass ----------------
__global__ __launch_bounds__(256) void k_final(const int* __restrict__ start,
                                               const int* __restrict__ srcs,
                                               const float4* __restrict__ nd4,
                                               const float2* __restrict__ y32,
                                               float* __restrict__ out) {
  const int tid = threadIdx.x;
  const int n = blockIdx.x * 16 + (tid >> 4);
  const int li = tid & 15;
  const int s = start[n], t = start[n + 1];
  const float ad = nd4[n].w;
  float den = 0.f, a0 = 0.f, a1 = 0.f;
  for (int ii = s + li; ii < t; ii += 16) {
    float4 vv = nd4[srcs[ii]];
    float p = __expf(lrelu(vv.x + ad));
    den += p;
    a0 = fmaf(p, vv.y, a0);
    a1 = fmaf(p, vv.z, a1);
  }
#pragma unroll
  for (int off = 1; off < 16; off <<= 1) {
    den += __shfl_xor(den, off, 64);
    a0 += __shfl_xor(a0, off, 64);
    a1 += __shfl_xor(a1, off, 64);
  }
  if (li == 0) {
    float2 y = y32[n];
    float inv = 1.f / (den + 1e-16f);
    out[2 * n] = fmaxf(fmaf(a0, inv, y.x), 0.f);
    out[2 * n + 1] = fmaxf(fmaf(a1, inv, y.y), 0.f);
  }
}

extern "C" void kernel_launch(void* const* d_in, const int* in_sizes, int n_in,
                              void* d_out, int out_size, void* d_ws, size_t ws_size,
                              hipStream_t stream) {
  const float* x = (const float*)d_in[0];
  const int* ei = (const int*)d_in[1];
  const float* bn1_g = (const float*)d_in[2];
  const float* bn1_b = (const float*)d_in[3];
  const float* lin1_W = (const float*)d_in[4];
  const float* lin1_b = (const float*)d_in[5];
  const float* con1_W = (const float*)d_in[6];
  const float* con1_as = (const float*)d_in[7];
  const float* con1_ad = (const float*)d_in[8];
  const float* con1_b = (const float*)d_in[9];
  const float* bn3_g = (const float*)d_in[10];
  const float* bn3_b = (const float*)d_in[11];
  const float* lin3_W = (const float*)d_in[12];
  const float* lin3_b = (const float*)d_in[13];
  const float* con3_W = (const float*)d_in[14];
  const float* con3_as = (const float*)d_in[15];
  const float* con3_ad = (const float*)d_in[16];
  const float* con3_b = (const float*)d_in[17];
  float* ws = (float*)d_ws;
  const int* srcA = ei;
  const int* dstA = ei + NE;

  float* S1 = ws + OFF_S1;
  float* S2 = ws + OFF_S2;
  int* counts = (int*)(ws + OFF_COUNTS);
  int* cursor = (int*)(ws + OFF_CURSOR);
  int* start = (int*)(ws + OFF_START);
  float* als = ws + OFF_ALS;
  float* ald = ws + OFF_ALD;
  int* srcs = (int*)(ws + OFF_SRCS);
  float2* y32 = (float2*)(ws + OFF_Y32);
  float4* nd4 = (float4*)(ws + OFF_ND4);
  unsigned short* Bfh = (unsigned short*)(ws + OFF_BFH);
  unsigned short* hbf = (unsigned short*)(ws + OFF_HBF);
  unsigned short* ylbf = (unsigned short*)(ws + OFF_YLBF);  // becomes x1 in place

  hipMemsetAsync(ws, 0, (size_t)ZERO_END * sizeof(float), stream);

  k_prep<<<4661, 256, 0, stream>>>(x, S1, S2, dstA, counts, lin1_W, con1_W, Bfh);
  k_gemm<<<dim3(2, 782), 256, 0, stream>>>(x, S1, S2, bn1_g, bn1_b, Bfh, ylbf, hbf,
                                           con1_as, con1_ad, als, ald);
  k_scan<<<49, 1024, 0, stream>>>(counts, start, cursor, S1, S2);
  k_scatter<<<3125, 256, 0, stream>>>(srcA, dstA, cursor, srcs);
  k_agg<<<12500, 256, 0, stream>>>((const ushort4*)hbf, (ushort4*)ylbf,
                                   (const float4*)als, (const float4*)ald, start,
                                   srcs, (const float4*)lin1_b,
                                   (const float4*)con1_b);
  k_bnstats2<<<1024, 256, 0, stream>>>(ylbf, S1, S2);
  k_node2<<<12500, 256, 0, stream>>>((const ushort4*)ylbf, S1, S2, bn3_g, bn3_b,
                                     (const float4*)lin3_W, (const float4*)con3_W,
                                     con3_as, con3_ad, lin3_b, con3_b, y32, nd4);
  k_final<<<3125, 256, 0, stream>>>(start, srcs, nd4, y32, (float*)d_out);
}